// Round 11
// baseline (260.120 us; speedup 1.0000x reference)
//
#include <hip/hip_runtime.h>
#include <hip/hip_bf16.h>
#include <stdint.h>

#define NQ 32
#define NCLS 5
#define SHOT 5
#define NIMG 57          // 32 query + 25 support
#define P1 7056          // 84*84
#define P2 1764          // 42*42
#define P3 441           // 21*21
#define MM (SHOT*P3)     // 2205
#define EPSB 1e-5f
#define SLOPE 0.2f
#define NEGINF -3.4e38f
#define NREP 32          // stats atomic replication factor
#define MSPAN 576        // sim m-range rows per block (36 tiles)
#define MRNG 4           // m-ranges (4*576 >= 2205)
#define MRNG2 8          // partial slots: m-range x m-half

typedef __attribute__((ext_vector_type(8))) short short8;
typedef __attribute__((ext_vector_type(4))) float f32x4;

__device__ inline float ldf(const float* p) { return *p; }
__device__ inline float ldf(const __hip_bfloat16* p) { return __bfloat162float(*p); }
__device__ inline void stf(float* p, float v) { *p = v; }
__device__ inline void stf(__hip_bfloat16* p, float v) { *p = __float2bfloat16(v); }

__device__ __forceinline__ unsigned short bf16bits(float v)
{
    __hip_bfloat16 h = __float2bfloat16(v);
    return *reinterpret_cast<unsigned short*>(&h);
}

// ---------------- all weight packs in one launch ----------------
__global__ void pack_all_k(const float* __restrict__ w1, const float* __restrict__ w2,
                           const float* __restrict__ w3, const float* __restrict__ w4,
                           unsigned short* __restrict__ wpk1, unsigned short* __restrict__ wpk2,
                           unsigned short* __restrict__ wpk3, unsigned short* __restrict__ wpk4)
{
    int i = blockIdx.x * 256 + threadIdx.x;
    if (i < 3 * 36864) {
        int set = i / 36864, ii = i - set * 36864;
        const float* w = (set == 0) ? w2 : (set == 1) ? w3 : w4;
        unsigned short* wpk = (set == 0) ? wpk2 : (set == 1) ? wpk3 : wpk4;
        int j = ii & 7, lane = (ii >> 3) & 63, chunk = ii >> 9;
        int nt = chunk & 3, half = (chunk >> 2) & 1, t = chunk >> 3;
        int co = nt * 16 + (lane & 15);
        int ci = half * 32 + (lane >> 4) * 8 + j;
        wpk[ii] = bf16bits(w[co * 576 + ci * 9 + t]);
    } else {
        int ii = i - 3 * 36864;
        if (ii >= 4096) return;
        int j = ii & 7, lane = (ii >> 3) & 63, c8 = ii >> 9;
        int nt = c8 & 3, f = c8 >> 2;
        int co = nt * 16 + (lane & 15), q = lane >> 4;
        int k = q * 8 + j;
        float val = 0.f;
        if (f == 0) {
            int t = k >> 2, ci = k & 3;
            if (ci < 3) val = w1[co * 27 + ci * 9 + t];
        } else if (k < 4) {
            int ci = k & 3;
            if (ci < 3) val = w1[co * 27 + ci * 9 + 8];
        }
        wpk1[ii] = bf16bits(val);
    }
}

// ---------------- MFMA conv1 3->64, stages NCHW fp32 directly, fused BN stats, bf16 out ----
__global__ __launch_bounds__(256) void conv1m_k(const float* __restrict__ in1,
                                                const float* __restrict__ in2,
                                                const unsigned short* __restrict__ wpk1,
                                                __hip_bfloat16* __restrict__ out,
                                                float* __restrict__ sums)
{
    constexpr int S = 84, P = P1, MBLK = 256, NB = 28, SPAN = MBLK + 2 * S + 2;  // 426
    __shared__ __align__(16) unsigned short ls4[SPAN * 4];   // 8 B per pixel [c0,c1,c2,0]
    __shared__ float qs[4][64], qs2[4][64];
    int img = blockIdx.x / NB;
    int p0 = (blockIdx.x % NB) * MBLK;
    int tid = threadIdx.x, lane = tid & 63, wv = tid >> 6;
    int col = lane & 15, quad = lane >> 4;
    const float* in = (img < NQ) ? in1 + (size_t)img * 3 * P1
                                 : in2 + (size_t)(img - NQ) * 3 * P1;
    for (int u = tid; u < SPAN; u += 256) {
        int p = p0 - S - 1 + u;
        union { unsigned short us[4]; uint2 u2; } o;
        o.u2 = (uint2){0u, 0u};
        if (p >= 0 && p < P) {
            o.us[0] = bf16bits(in[p]);
            o.us[1] = bf16bits(in[P1 + p]);
            o.us[2] = bf16bits(in[2 * P1 + p]);
        }
        *(uint2*)(ls4 + u * 4) = o.u2;
    }
    const short8* wb = (const short8*)wpk1;
    short8 b0[4], b1[4];
    #pragma unroll
    for (int nt = 0; nt < 4; ++nt) {
        b0[nt] = wb[(size_t)(nt * 64 + lane)];
        b1[nt] = wb[(size_t)((4 + nt) * 64 + lane)];
    }
    int t0 = 2 * quad, t1 = t0 + 1;
    int d0 = (t0 / 3 - 1) * S + (t0 % 3 - 1);
    int d1 = (t1 / 3 - 1) * S + (t1 % 3 - 1);
    const int d8 = S + 1;
    int tx0 = t0 % 3, tx1 = t1 % 3;
    __syncthreads();
    f32x4 acc[4][4];
    #pragma unroll
    for (int mt = 0; mt < 4; ++mt)
        #pragma unroll
        for (int nt = 0; nt < 4; ++nt) acc[mt][nt] = (f32x4){0.f, 0.f, 0.f, 0.f};
    #pragma unroll
    for (int mt = 0; mt < 4; ++mt) {
        int pl = wv * 64 + mt * 16 + col;
        int xm = (p0 + pl) % S;
        int base = pl + S + 1;
        uint2 h0 = *(const uint2*)(ls4 + (base + d0) * 4);
        uint2 h1 = *(const uint2*)(ls4 + (base + d1) * 4);
        uint2 h8 = *(const uint2*)(ls4 + (base + d8) * 4);
        bool ok0 = (tx0 == 0) ? (xm >= 1) : ((tx0 == 2) ? (xm <= S - 2) : true);
        bool ok1 = (tx1 == 0) ? (xm >= 1) : ((tx1 == 2) ? (xm <= S - 2) : true);
        bool ok8 = (quad == 0) && (xm <= S - 2);
        if (!ok0) h0 = (uint2){0u, 0u};
        if (!ok1) h1 = (uint2){0u, 0u};
        if (!ok8) h8 = (uint2){0u, 0u};
        union { uint4 u; short8 s; } ca, cb;
        ca.u = (uint4){h0.x, h0.y, h1.x, h1.y};
        cb.u = (uint4){h8.x, h8.y, 0u, 0u};
        #pragma unroll
        for (int nt = 0; nt < 4; ++nt) {
            acc[mt][nt] = __builtin_amdgcn_mfma_f32_16x16x32_bf16(ca.s, b0[nt], acc[mt][nt], 0, 0, 0);
            acc[mt][nt] = __builtin_amdgcn_mfma_f32_16x16x32_bf16(cb.s, b1[nt], acc[mt][nt], 0, 0, 0);
        }
    }
    float s[4] = {0.f, 0.f, 0.f, 0.f}, s2[4] = {0.f, 0.f, 0.f, 0.f};
    __hip_bfloat16* ob = out + (size_t)img * P * 64;
    #pragma unroll
    for (int mt = 0; mt < 4; ++mt) {
        int tb = p0 + wv * 64 + mt * 16 + quad * 4;
        #pragma unroll
        for (int reg = 0; reg < 4; ++reg) {
            int pr = tb + reg;
            if (pr < P) {
                #pragma unroll
                for (int nt = 0; nt < 4; ++nt) {
                    float v = acc[mt][nt][reg];
                    ob[(size_t)pr * 64 + nt * 16 + col] = __float2bfloat16(v);
                    s[nt] += v;
                    s2[nt] = fmaf(v, v, s2[nt]);
                }
            }
        }
    }
    #pragma unroll
    for (int d = 16; d < 64; d <<= 1)
        #pragma unroll
        for (int nt = 0; nt < 4; ++nt) {
            s[nt] += __shfl_xor(s[nt], d, 64);
            s2[nt] += __shfl_xor(s2[nt], d, 64);
        }
    if (quad == 0) {
        #pragma unroll
        for (int nt = 0; nt < 4; ++nt) {
            qs[wv][nt * 16 + col] = s[nt];
            qs2[wv][nt * 16 + col] = s2[nt];
        }
    }
    __syncthreads();
    if (wv == 0) {
        int g = (img < NQ) ? 0 : 1 + (img - NQ) / SHOT;
        int rep = blockIdx.x & (NREP - 1);
        float ts = qs[0][lane] + qs[1][lane] + qs[2][lane] + qs[3][lane];
        float ts2 = qs2[0][lane] + qs2[1][lane] + qs2[2][lane] + qs2[3][lane];
        float* base = sums + ((size_t)(g * 64 + lane) * 2) * NREP + rep;
        atomicAdd(base, ts);
        atomicAdd(base + NREP, ts2);
    }
}

// ---------------- MFMA conv 64->64, channels-last bf16 in, OT out, fused BN stats ----------
template <int S, int MBLK, typename OT>
__global__ __launch_bounds__(256) void conv64m_k(const unsigned short* __restrict__ in,
                                                 const unsigned short* __restrict__ wpk,
                                                 OT* __restrict__ out,
                                                 float* __restrict__ sums)
{
    constexpr int P = S * S;
    constexpr int MT = MBLK / 64;
    constexpr int NB = (P + MBLK - 1) / MBLK;
    constexpr int SPAN = MBLK + 2 * S + 2;
    __shared__ __align__(16) unsigned short ls[SPAN * 72];
    __shared__ float qs[4][64], qs2[4][64];
    int img = blockIdx.x / NB;
    int p0 = (blockIdx.x % NB) * MBLK;
    int tid = threadIdx.x;
    int lane = tid & 63, wv = tid >> 6;
    int col = lane & 15, quad = lane >> 4;
    const unsigned short* ib = in + (size_t)img * P * 64;
    for (int u = tid; u < SPAN * 8; u += 256) {
        int pix = u >> 3, part = u & 7;
        int p = p0 - S - 1 + pix;
        short8 v = {0, 0, 0, 0, 0, 0, 0, 0};
        if (p >= 0 && p < P) v = *(const short8*)(ib + (size_t)p * 64 + part * 8);
        *(short8*)(ls + pix * 72 + part * 8) = v;
    }
    __syncthreads();
    f32x4 acc[MT][4];
    #pragma unroll
    for (int mt = 0; mt < MT; ++mt)
        #pragma unroll
        for (int nt = 0; nt < 4; ++nt) acc[mt][nt] = (f32x4){0.f, 0.f, 0.f, 0.f};
    bool mok0[MT], mok2[MT];
    #pragma unroll
    for (int mt = 0; mt < MT; ++mt) {
        int xm = (p0 + wv * (MT * 16) + mt * 16 + col) % S;
        mok0[mt] = xm >= 1;
        mok2[mt] = xm <= S - 2;
    }
    const short8* wb = (const short8*)wpk;
    #pragma unroll
    for (int ky = 0; ky < 3; ++ky) {
        #pragma unroll
        for (int kx = 0; kx < 3; ++kx) {
            int t = ky * 3 + kx;
            int d = (ky - 1) * S + (kx - 1);
            #pragma unroll
            for (int half = 0; half < 2; ++half) {
                short8 b[4];
                #pragma unroll
                for (int nt = 0; nt < 4; ++nt)
                    b[nt] = wb[((t * 2 + half) * 4 + nt) * 64 + lane];
                #pragma unroll
                for (int mt = 0; mt < MT; ++mt) {
                    int idx = wv * (MT * 16) + mt * 16 + col + S + 1 + d;
                    short8 a = *(const short8*)(ls + idx * 72 + half * 32 + quad * 8);
                    bool ok = (kx == 0) ? mok0[mt] : (kx == 2) ? mok2[mt] : true;
                    if (!ok) a = (short8){0, 0, 0, 0, 0, 0, 0, 0};
                    #pragma unroll
                    for (int nt = 0; nt < 4; ++nt)
                        acc[mt][nt] = __builtin_amdgcn_mfma_f32_16x16x32_bf16(a, b[nt], acc[mt][nt], 0, 0, 0);
                }
            }
        }
    }
    float s[4] = {0.f, 0.f, 0.f, 0.f}, s2[4] = {0.f, 0.f, 0.f, 0.f};
    OT* ob = out + (size_t)img * P * 64;
    #pragma unroll
    for (int mt = 0; mt < MT; ++mt) {
        int tb = p0 + wv * (MT * 16) + mt * 16 + quad * 4;
        #pragma unroll
        for (int reg = 0; reg < 4; ++reg) {
            int pr = tb + reg;
            if (pr < P) {
                #pragma unroll
                for (int nt = 0; nt < 4; ++nt) {
                    float v = acc[mt][nt][reg];
                    stf(ob + (size_t)pr * 64 + nt * 16 + col, v);
                    s[nt] += v;
                    s2[nt] = fmaf(v, v, s2[nt]);
                }
            }
        }
    }
    #pragma unroll
    for (int d = 16; d < 64; d <<= 1)
        #pragma unroll
        for (int nt = 0; nt < 4; ++nt) {
            s[nt] += __shfl_xor(s[nt], d, 64);
            s2[nt] += __shfl_xor(s2[nt], d, 64);
        }
    if (quad == 0) {
        #pragma unroll
        for (int nt = 0; nt < 4; ++nt) {
            qs[wv][nt * 16 + col] = s[nt];
            qs2[wv][nt * 16 + col] = s2[nt];
        }
    }
    __syncthreads();
    if (wv == 0) {
        int g = (img < NQ) ? 0 : 1 + (img - NQ) / SHOT;
        int rep = blockIdx.x & (NREP - 1);
        float ts = qs[0][lane] + qs[1][lane] + qs[2][lane] + qs[3][lane];
        float ts2 = qs2[0][lane] + qs2[1][lane] + qs2[2][lane] + qs2[3][lane];
        float* base = sums + ((size_t)(g * 64 + lane) * 2) * NREP + rep;
        atomicAdd(base, ts);
        atomicAdd(base + NREP, ts2);
    }
}

// fold (mean, invstd, gamma, beta) -> (a, b): y = x*a + b   (sums has NREP replicas)
__global__ void finalize_k(const float* __restrict__ sums, float* __restrict__ ms,
                           const float* __restrict__ gamma, const float* __restrict__ beta, int P)
{
    int i = blockIdx.x * blockDim.x + threadIdx.x;
    if (i >= 6 * 64) return;
    int g = i >> 6, c = i & 63;
    const float* ps = sums + (size_t)i * 2 * NREP;
    float s = 0.f, s2 = 0.f;
    #pragma unroll
    for (int r = 0; r < NREP; ++r) { s += ps[r]; s2 += ps[NREP + r]; }
    float cnt = (float)((g == 0 ? NQ : SHOT) * P);
    float mean = s / cnt;
    float var = s2 / cnt - mean * mean;
    float a = rsqrtf(var + EPSB) * gamma[c];
    ms[i * 2] = a;
    ms[i * 2 + 1] = fmaf(-mean, a, beta[c]);
}

// ---------------- BN + LeakyReLU + 2x2 maxpool -> bf16 ----------------
template <typename T>
__global__ __launch_bounds__(256) void bnpool_k(const T* __restrict__ x, const float* __restrict__ ms,
                                                __hip_bfloat16* __restrict__ out, int Win)
{
    int Wout = Win >> 1, Pout = Wout * Wout;
    size_t idx = (size_t)blockIdx.x * 256 + threadIdx.x;
    size_t total = (size_t)NIMG * Pout * 64;
    if (idx >= total) return;
    int c = (int)(idx & 63);
    size_t t = idx >> 6;
    int p = (int)(t % Pout);
    int img = (int)(t / Pout);
    int y = p / Wout, xo = p - y * Wout;
    int g = (img < NQ) ? 0 : 1 + (img - NQ) / SHOT;
    float a = ms[(g * 64 + c) * 2], bb = ms[(g * 64 + c) * 2 + 1];
    const T* base = x + (((size_t)img * Win + 2 * y) * Win + 2 * xo) * 64 + c;
    float mx = -3.4e38f;
    #pragma unroll
    for (int dy = 0; dy < 2; ++dy)
        #pragma unroll
        for (int dx = 0; dx < 2; ++dx) {
            float v = ldf(base + ((size_t)dy * Win + dx) * 64);
            v = fmaf(v, a, bb);
            v = v >= 0.f ? v : SLOPE * v;
            mx = fmaxf(mx, v);
        }
    out[idx] = __float2bfloat16(mx);
}

// ---------------- BN + LeakyReLU (elementwise, stage 3) -> bf16 ----------------
__global__ __launch_bounds__(256) void bnact_k(const float* __restrict__ x, const float* __restrict__ ms,
                                               __hip_bfloat16* __restrict__ out)
{
    size_t idx = (size_t)blockIdx.x * 256 + threadIdx.x;
    size_t total = (size_t)NIMG * P3 * 64;
    if (idx >= total) return;
    int c = (int)(idx & 63);
    int img = (int)(idx >> 6) / P3;
    int g = (img < NQ) ? 0 : 1 + (img - NQ) / SHOT;
    float v = fmaf(x[idx], ms[(g * 64 + c) * 2], ms[(g * 64 + c) * 2 + 1]);
    out[idx] = __float2bfloat16(v >= 0.f ? v : SLOPE * v);
}

// ---------------- BN4 + LeakyReLU + per-pixel L2-normalize -> bf16 ----------------
__global__ __launch_bounds__(256) void bnnorm_k(const float* __restrict__ x, const float* __restrict__ ms,
                                                __hip_bfloat16* __restrict__ out)
{
    int lane = threadIdx.x & 63, wvr = threadIdx.x >> 6;
    int pix = blockIdx.x * 4 + wvr;        // one wave per pixel
    if (pix >= NIMG * P3) return;
    int img = pix / P3;
    int g = (img < NQ) ? 0 : 1 + (img - NQ) / SHOT;
    float v = fmaf(x[(size_t)pix * 64 + lane], ms[(g * 64 + lane) * 2], ms[(g * 64 + lane) * 2 + 1]);
    v = v >= 0.f ? v : SLOPE * v;
    float ss = v * v;
    #pragma unroll
    for (int d = 32; d > 0; d >>= 1) ss += __shfl_xor(ss, d, 64);
    out[(size_t)pix * 64 + lane] = __float2bfloat16(v * rsqrtf(ss));
}

// ---------------- similarity v7: m-split blocks, 2q-tiles x 2m-tiles per wave, VGPR-resident ----
__device__ __forceinline__ void ins3(float v, float& t0, float& t1, float& t2)
{
    float n1 = __builtin_amdgcn_fmed3f(v, t0, t1);
    float n2 = __builtin_amdgcn_fmed3f(v, t1, t2);
    t0 = fmaxf(t0, v);
    t1 = n1;
    t2 = n2;
}

// grid: bq(32) x n(5) x qb(7) x mr(4) = 4480 blocks; block: 64q x 576-row m-range
// wave wv: q-half qh=wv&1 (32q), m-half mh=wv>>1 (tiles {0,1} or {2,3} of each 64-row chunk)
// part layout: ((((bq*5+n)*7+qb)*8 + mr*2+mh)*64 + ql)*3
__global__ __launch_bounds__(256, 4) void sim_part_k(const __hip_bfloat16* __restrict__ fhat,
                                                     float* __restrict__ part)
{
    __shared__ __align__(16) unsigned short sl[64 * 72];   // 64 m-rows, 72-ushort stride
    int t = blockIdx.x;
    int mr = t & 3;
    int qb = (t >> 2) % 7;
    int n = (t / 28) % NCLS;
    int bq = t / (28 * NCLS);
    int tid = threadIdx.x, lane = tid & 63, wv = tid >> 6;
    int col = lane & 15, quad = lane >> 4;
    int qh = wv & 1, mh = wv >> 1;
    short8 a0[2], a1[2];
    #pragma unroll
    for (int qt = 0; qt < 2; ++qt) {
        int q = qb * 64 + qh * 32 + qt * 16 + col;
        int qc = q < P3 ? q : P3 - 1;
        const unsigned short* qp = (const unsigned short*)fhat + ((size_t)bq * P3 + qc) * 64;
        a0[qt] = *(const short8*)(qp + quad * 8);
        a1[qt] = *(const short8*)(qp + 32 + quad * 8);
    }
    const unsigned short* sp = (const unsigned short*)fhat + (size_t)(NQ + n * SHOT) * P3 * 64;
    int m_lo = mr * MSPAN;
    int m_cnt = MM - m_lo; if (m_cnt > MSPAN) m_cnt = MSPAN;
    int nch = (m_cnt + 63) >> 6;
    float t0[2][4], t1[2][4], t2[2][4];
    #pragma unroll
    for (int qt = 0; qt < 2; ++qt)
        #pragma unroll
        for (int r = 0; r < 4; ++r) { t0[qt][r] = NEGINF; t1[qt][r] = NEGINF; t2[qt][r] = NEGINF; }
    for (int c = 0; c < nch; ++c) {
        int m0 = m_lo + c * 64;
        __syncthreads();
        #pragma unroll
        for (int pass = 0; pass < 2; ++pass) {
            int row = (tid >> 3) + pass * 32;
            int cc = (tid & 7) * 8;
            int m = m0 + row;
            short8 vv = {0, 0, 0, 0, 0, 0, 0, 0};
            if (m < MM) vv = *(const short8*)(sp + (size_t)m * 64 + cc);
            *(short8*)(sl + row * 72 + cc) = vv;
        }
        __syncthreads();
        #pragma unroll
        for (int j = 0; j < 2; ++j) {
            int mt = mh * 2 + j;
            int mbase = m0 + mt * 16;
            if (mbase >= MM) continue;          // wave-uniform: fully-invalid tile
            const unsigned short* sr = sl + (mt * 16 + col) * 72;
            short8 b0 = *(const short8*)(sr + quad * 8);
            short8 b1 = *(const short8*)(sr + 32 + quad * 8);
            if (mbase + 15 < MM) {
                #pragma unroll
                for (int qt = 0; qt < 2; ++qt) {
                    f32x4 acc = {0.f, 0.f, 0.f, 0.f};
                    acc = __builtin_amdgcn_mfma_f32_16x16x32_bf16(a0[qt], b0, acc, 0, 0, 0);
                    acc = __builtin_amdgcn_mfma_f32_16x16x32_bf16(a1[qt], b1, acc, 0, 0, 0);
                    #pragma unroll
                    for (int r = 0; r < 4; ++r) ins3(acc[r], t0[qt][r], t1[qt][r], t2[qt][r]);
                }
            } else {
                float bias = (mbase + col < MM) ? 0.f : NEGINF;
                #pragma unroll
                for (int qt = 0; qt < 2; ++qt) {
                    f32x4 acc = {0.f, 0.f, 0.f, 0.f};
                    acc = __builtin_amdgcn_mfma_f32_16x16x32_bf16(a0[qt], b0, acc, 0, 0, 0);
                    acc = __builtin_amdgcn_mfma_f32_16x16x32_bf16(a1[qt], b1, acc, 0, 0, 0);
                    #pragma unroll
                    for (int r = 0; r < 4; ++r) ins3(acc[r] + bias, t0[qt][r], t1[qt][r], t2[qt][r]);
                }
            }
        }
    }
    // merge top-3 across the 16 col-lanes (m), same q per (qt, quad, r)
    #pragma unroll
    for (int d = 1; d < 16; d <<= 1)
        #pragma unroll
        for (int qt = 0; qt < 2; ++qt)
            #pragma unroll
            for (int r = 0; r < 4; ++r) {
                float u0 = __shfl_xor(t0[qt][r], d, 64);
                float u1 = __shfl_xor(t1[qt][r], d, 64);
                float u2 = __shfl_xor(t2[qt][r], d, 64);
                ins3(u0, t0[qt][r], t1[qt][r], t2[qt][r]);
                ins3(u1, t0[qt][r], t1[qt][r], t2[qt][r]);
                ins3(u2, t0[qt][r], t1[qt][r], t2[qt][r]);
            }
    if (col == 0) {
        int mr2 = mr * 2 + mh;
        #pragma unroll
        for (int qt = 0; qt < 2; ++qt)
            #pragma unroll
            for (int r = 0; r < 4; ++r) {
                int ql = qh * 32 + qt * 16 + quad * 4 + r;
                float* pp = part + ((((size_t)(bq * NCLS + n) * 7 + qb) * MRNG2 + mr2) * 64 + ql) * 3;
                pp[0] = t0[qt][r];
                pp[1] = t1[qt][r];
                pp[2] = t2[qt][r];
            }
    }
}

// one block per (bq, n): merge 8 m-subrange partials per q, sum top-3, write out directly
__global__ __launch_bounds__(256) void sim_merge_k(const float* __restrict__ part,
                                                   float* __restrict__ out)
{
    __shared__ float red[4];
    int b = blockIdx.x;                    // bq*NCLS + n
    int tid = threadIdx.x, lane = tid & 63, wv = tid >> 6;
    float s = 0.f;
    for (int q = tid; q < P3; q += 256) {
        int qb = q >> 6, ql = q & 63;
        const float* pp = part + (((size_t)b * 7 + qb) * MRNG2 * 64 + ql) * 3;
        float v0 = pp[0], v1 = pp[1], v2 = pp[2];
        #pragma unroll
        for (int mr = 1; mr < MRNG2; ++mr) {
            const float* pm = pp + (size_t)mr * 192;
            ins3(pm[0], v0, v1, v2);
            ins3(pm[1], v0, v1, v2);
            ins3(pm[2], v0, v1, v2);
        }
        s += v0 + v1 + v2;
    }
    #pragma unroll
    for (int d = 32; d > 0; d >>= 1) s += __shfl_xor(s, d, 64);
    if (lane == 0) red[wv] = s;
    __syncthreads();
    if (tid == 0) out[b] = red[0] + red[1] + red[2] + red[3];
}

extern "C" void kernel_launch(void* const* d_in, const int* in_sizes, int n_in,
                              void* d_out, int out_size, void* d_ws, size_t ws_size,
                              hipStream_t stream)
{
    const float* input1 = (const float*)d_in[0];
    const float* input2 = (const float*)d_in[1];
    const float* w1 = (const float*)d_in[2];
    const float* g1 = (const float*)d_in[3];
    const float* b1 = (const float*)d_in[4];
    const float* w2 = (const float*)d_in[5];
    const float* g2 = (const float*)d_in[6];
    const float* b2 = (const float*)d_in[7];
    const float* w3 = (const float*)d_in[8];
    const float* g3 = (const float*)d_in[9];
    const float* b3 = (const float*)d_in[10];
    const float* w4 = (const float*)d_in[11];
    const float* g4 = (const float*)d_in[12];
    const float* b4 = (const float*)d_in[13];
    float* out = (float*)d_out;

    char* w8 = (char*)d_ws;
    const size_t oB = 51480576;
    const size_t oT = oB + 12870144;
    const size_t STG = 6 * 64 * 2 * NREP * sizeof(float);   // 98304 B per stage
    __hip_bfloat16* conv1raw = (__hip_bfloat16*)(w8 + 0);
    __hip_bfloat16* conv2raw = (__hip_bfloat16*)(w8 + 0);   // bf16 (12.87MB)
    float* conv3raw = (float*)(w8 + 0);
    __hip_bfloat16* act3 = (__hip_bfloat16*)(w8 + 6435072);
    float* conv4raw = (float*)(w8 + 9652608);
    __hip_bfloat16* fhat = (__hip_bfloat16*)(w8 + 16087680);
    __hip_bfloat16* pooled1 = (__hip_bfloat16*)(w8 + oB);     // 12.87MB
    __hip_bfloat16* pooled2 = (__hip_bfloat16*)(w8 + oB);     // reuse (3.2MB)
    float* sums = (float*)(w8 + oT);                          // 4 stages x 98304 B
    float* ms = (float*)(w8 + oT + 4 * STG);
    unsigned short* wpk2 = (unsigned short*)(w8 + oT + 4 * STG + 12288);
    unsigned short* wpk3 = (unsigned short*)(w8 + oT + 4 * STG + 12288 + 73728);
    unsigned short* wpk4 = (unsigned short*)(w8 + oT + 4 * STG + 12288 + 147456);
    unsigned short* wpk1 = (unsigned short*)(w8 + oT + 4 * STG + 12288 + 221184);
    const size_t oP = oT + 4 * STG + 12288 + 221184 + 8192;
    float* part = (float*)(w8 + oP);                          // 32*5*7*8*64*3 f32 = 6.88MB
    if (ws_size < oP + (size_t)NQ * NCLS * 7 * MRNG2 * 64 * 3 * sizeof(float)) return;
    float* sums1 = sums;
    float* sums2 = sums + 6 * 64 * 2 * NREP;
    float* sums3 = sums2 + 6 * 64 * 2 * NREP;
    float* sums4 = sums3 + 6 * 64 * 2 * NREP;

    hipMemsetAsync(sums, 0, 4 * STG, stream);

    pack_all_k<<<448, 256, 0, stream>>>(w1, w2, w3, w4, wpk1, wpk2, wpk3, wpk4);

    // stage 1: conv1 MFMA (+stats) -> finalize -> BN+LReLU+pool (84 -> 42)
    conv1m_k<<<NIMG * 28, 256, 0, stream>>>(input1, input2, wpk1, conv1raw, sums1);
    finalize_k<<<2, 256, 0, stream>>>(sums1, ms + 0, g1, b1, P1);
    bnpool_k<__hip_bfloat16><<<25137, 256, 0, stream>>>(conv1raw, ms + 0, pooled1, 84);
    // stage 2: conv2 MFMA (+stats, bf16 out) -> finalize -> BN+LReLU+pool (42 -> 21)
    conv64m_k<42, 256, __hip_bfloat16><<<NIMG * 7, 256, 0, stream>>>(
        (const unsigned short*)pooled1, wpk2, conv2raw, sums2);
    finalize_k<<<2, 256, 0, stream>>>(sums2, ms + 768, g2, b2, P2);
    bnpool_k<__hip_bfloat16><<<6285, 256, 0, stream>>>(conv2raw, ms + 768, pooled2, 42);
    // stage 3: conv3 MFMA (+stats) -> finalize -> BN+LReLU
    conv64m_k<21, 128, float><<<NIMG * 4, 256, 0, stream>>>(
        (const unsigned short*)pooled2, wpk3, conv3raw, sums3);
    finalize_k<<<2, 256, 0, stream>>>(sums3, ms + 1536, g3, b3, P3);
    bnact_k<<<6285, 256, 0, stream>>>(conv3raw, ms + 1536, act3);
    // stage 4: conv4 MFMA (+stats) -> finalize -> BN+LReLU+normalize -> bf16 fhat
    conv64m_k<21, 128, float><<<NIMG * 4, 256, 0, stream>>>(
        (const unsigned short*)act3, wpk4, conv4raw, sums4);
    finalize_k<<<2, 256, 0, stream>>>(sums4, ms + 2304, g4, b4, P3);
    bnnorm_k<<<6285, 256, 0, stream>>>(conv4raw, ms + 2304, fhat);
    // similarity: partial top-3 over m-subranges, then merge (writes d_out directly)
    sim_part_k<<<NQ * NCLS * 7 * MRNG, 256, 0, stream>>>(fhat, part);
    sim_merge_k<<<NQ * NCLS, 256, 0, stream>>>(part, out);
}

// Round 12
// 243.570 us; speedup vs baseline: 1.0679x; 1.0679x over previous
//
#include <hip/hip_runtime.h>
#include <hip/hip_bf16.h>
#include <stdint.h>

#define NQ 32
#define NCLS 5
#define SHOT 5
#define NIMG 57          // 32 query + 25 support
#define P1 7056          // 84*84
#define P2 1764          // 42*42
#define P3 441           // 21*21
#define MM (SHOT*P3)     // 2205
#define EPSB 1e-5f
#define SLOPE 0.2f
#define NEGINF -3.4e38f
#define NREP 32          // stats atomic replication factor
#define MSPAN 576        // sim m-range rows per block (36 tiles)
#define MRNG 4           // m-ranges (4*576 >= 2205)

typedef __attribute__((ext_vector_type(8))) short short8;
typedef __attribute__((ext_vector_type(4))) float f32x4;

__device__ inline float ldf(const float* p) { return *p; }
__device__ inline float ldf(const __hip_bfloat16* p) { return __bfloat162float(*p); }
__device__ inline void stf(float* p, float v) { *p = v; }
__device__ inline void stf(__hip_bfloat16* p, float v) { *p = __float2bfloat16(v); }

__device__ __forceinline__ unsigned short bf16bits(float v)
{
    __hip_bfloat16 h = __float2bfloat16(v);
    return *reinterpret_cast<unsigned short*>(&h);
}

// ---------------- all weight packs + zero stats sums, one launch ----------------
__global__ void pack_all_k(const float* __restrict__ w1, const float* __restrict__ w2,
                           const float* __restrict__ w3, const float* __restrict__ w4,
                           unsigned short* __restrict__ wpk1, unsigned short* __restrict__ wpk2,
                           unsigned short* __restrict__ wpk3, unsigned short* __restrict__ wpk4,
                           float* __restrict__ sums)
{
    int i = blockIdx.x * 256 + threadIdx.x;
    if (i < 4 * 6 * 64 * 2 * NREP) sums[i] = 0.f;   // zero all 4 stages' stat sums
    if (i < 3 * 36864) {
        int set = i / 36864, ii = i - set * 36864;
        const float* w = (set == 0) ? w2 : (set == 1) ? w3 : w4;
        unsigned short* wpk = (set == 0) ? wpk2 : (set == 1) ? wpk3 : wpk4;
        int j = ii & 7, lane = (ii >> 3) & 63, chunk = ii >> 9;
        int nt = chunk & 3, half = (chunk >> 2) & 1, t = chunk >> 3;
        int co = nt * 16 + (lane & 15);
        int ci = half * 32 + (lane >> 4) * 8 + j;
        wpk[ii] = bf16bits(w[co * 576 + ci * 9 + t]);
    } else {
        int ii = i - 3 * 36864;
        if (ii >= 4096) return;
        int j = ii & 7, lane = (ii >> 3) & 63, c8 = ii >> 9;
        int nt = c8 & 3, f = c8 >> 2;
        int co = nt * 16 + (lane & 15), q = lane >> 4;
        int k = q * 8 + j;
        float val = 0.f;
        if (f == 0) {
            int t = k >> 2, ci = k & 3;
            if (ci < 3) val = w1[co * 27 + ci * 9 + t];
        } else if (k < 4) {
            int ci = k & 3;
            if (ci < 3) val = w1[co * 27 + ci * 9 + 8];
        }
        wpk1[ii] = bf16bits(val);
    }
}

// ---------------- MFMA conv1 3->64, stages NCHW fp32 directly, fused BN stats, bf16 out ----
__global__ __launch_bounds__(256) void conv1m_k(const float* __restrict__ in1,
                                                const float* __restrict__ in2,
                                                const unsigned short* __restrict__ wpk1,
                                                __hip_bfloat16* __restrict__ out,
                                                float* __restrict__ sums)
{
    constexpr int S = 84, P = P1, MBLK = 256, NB = 28, SPAN = MBLK + 2 * S + 2;  // 426
    __shared__ __align__(16) unsigned short ls4[SPAN * 4];   // 8 B per pixel [c0,c1,c2,0]
    __shared__ float qs[4][64], qs2[4][64];
    int img = blockIdx.x / NB;
    int p0 = (blockIdx.x % NB) * MBLK;
    int tid = threadIdx.x, lane = tid & 63, wv = tid >> 6;
    int col = lane & 15, quad = lane >> 4;
    const float* in = (img < NQ) ? in1 + (size_t)img * 3 * P1
                                 : in2 + (size_t)(img - NQ) * 3 * P1;
    for (int u = tid; u < SPAN; u += 256) {
        int p = p0 - S - 1 + u;
        union { unsigned short us[4]; uint2 u2; } o;
        o.u2 = (uint2){0u, 0u};
        if (p >= 0 && p < P) {
            o.us[0] = bf16bits(in[p]);
            o.us[1] = bf16bits(in[P1 + p]);
            o.us[2] = bf16bits(in[2 * P1 + p]);
        }
        *(uint2*)(ls4 + u * 4) = o.u2;
    }
    const short8* wb = (const short8*)wpk1;
    short8 b0[4], b1[4];
    #pragma unroll
    for (int nt = 0; nt < 4; ++nt) {
        b0[nt] = wb[(size_t)(nt * 64 + lane)];
        b1[nt] = wb[(size_t)((4 + nt) * 64 + lane)];
    }
    int t0 = 2 * quad, t1 = t0 + 1;
    int d0 = (t0 / 3 - 1) * S + (t0 % 3 - 1);
    int d1 = (t1 / 3 - 1) * S + (t1 % 3 - 1);
    const int d8 = S + 1;
    int tx0 = t0 % 3, tx1 = t1 % 3;
    __syncthreads();
    f32x4 acc[4][4];
    #pragma unroll
    for (int mt = 0; mt < 4; ++mt)
        #pragma unroll
        for (int nt = 0; nt < 4; ++nt) acc[mt][nt] = (f32x4){0.f, 0.f, 0.f, 0.f};
    #pragma unroll
    for (int mt = 0; mt < 4; ++mt) {
        int pl = wv * 64 + mt * 16 + col;
        int xm = (p0 + pl) % S;
        int base = pl + S + 1;
        uint2 h0 = *(const uint2*)(ls4 + (base + d0) * 4);
        uint2 h1 = *(const uint2*)(ls4 + (base + d1) * 4);
        uint2 h8 = *(const uint2*)(ls4 + (base + d8) * 4);
        bool ok0 = (tx0 == 0) ? (xm >= 1) : ((tx0 == 2) ? (xm <= S - 2) : true);
        bool ok1 = (tx1 == 0) ? (xm >= 1) : ((tx1 == 2) ? (xm <= S - 2) : true);
        bool ok8 = (quad == 0) && (xm <= S - 2);
        if (!ok0) h0 = (uint2){0u, 0u};
        if (!ok1) h1 = (uint2){0u, 0u};
        if (!ok8) h8 = (uint2){0u, 0u};
        union { uint4 u; short8 s; } ca, cb;
        ca.u = (uint4){h0.x, h0.y, h1.x, h1.y};
        cb.u = (uint4){h8.x, h8.y, 0u, 0u};
        #pragma unroll
        for (int nt = 0; nt < 4; ++nt) {
            acc[mt][nt] = __builtin_amdgcn_mfma_f32_16x16x32_bf16(ca.s, b0[nt], acc[mt][nt], 0, 0, 0);
            acc[mt][nt] = __builtin_amdgcn_mfma_f32_16x16x32_bf16(cb.s, b1[nt], acc[mt][nt], 0, 0, 0);
        }
    }
    float s[4] = {0.f, 0.f, 0.f, 0.f}, s2[4] = {0.f, 0.f, 0.f, 0.f};
    __hip_bfloat16* ob = out + (size_t)img * P * 64;
    #pragma unroll
    for (int mt = 0; mt < 4; ++mt) {
        int tb = p0 + wv * 64 + mt * 16 + quad * 4;
        #pragma unroll
        for (int reg = 0; reg < 4; ++reg) {
            int pr = tb + reg;
            if (pr < P) {
                #pragma unroll
                for (int nt = 0; nt < 4; ++nt) {
                    float v = acc[mt][nt][reg];
                    ob[(size_t)pr * 64 + nt * 16 + col] = __float2bfloat16(v);
                    s[nt] += v;
                    s2[nt] = fmaf(v, v, s2[nt]);
                }
            }
        }
    }
    #pragma unroll
    for (int d = 16; d < 64; d <<= 1)
        #pragma unroll
        for (int nt = 0; nt < 4; ++nt) {
            s[nt] += __shfl_xor(s[nt], d, 64);
            s2[nt] += __shfl_xor(s2[nt], d, 64);
        }
    if (quad == 0) {
        #pragma unroll
        for (int nt = 0; nt < 4; ++nt) {
            qs[wv][nt * 16 + col] = s[nt];
            qs2[wv][nt * 16 + col] = s2[nt];
        }
    }
    __syncthreads();
    if (wv == 0) {
        int g = (img < NQ) ? 0 : 1 + (img - NQ) / SHOT;
        int rep = blockIdx.x & (NREP - 1);
        float ts = qs[0][lane] + qs[1][lane] + qs[2][lane] + qs[3][lane];
        float ts2 = qs2[0][lane] + qs2[1][lane] + qs2[2][lane] + qs2[3][lane];
        float* base = sums + ((size_t)(g * 64 + lane) * 2) * NREP + rep;
        atomicAdd(base, ts);
        atomicAdd(base + NREP, ts2);
    }
}

// ---------------- MFMA conv 64->64; staging: bf16 raw OR fp32+BN+LReLU (fused bnact) -------
template <int S, int MBLK, bool BNIN, typename OT>
__global__ __launch_bounds__(256) void conv64m_k(const void* __restrict__ inv,
                                                 const unsigned short* __restrict__ wpk,
                                                 OT* __restrict__ out,
                                                 float* __restrict__ sums,
                                                 const float* __restrict__ msin)
{
    constexpr int P = S * S;
    constexpr int MT = MBLK / 64;
    constexpr int NB = (P + MBLK - 1) / MBLK;
    constexpr int SPAN = MBLK + 2 * S + 2;
    __shared__ __align__(16) unsigned short ls[SPAN * 72];
    __shared__ float qs[4][64], qs2[4][64];
    int img = blockIdx.x / NB;
    int p0 = (blockIdx.x % NB) * MBLK;
    int tid = threadIdx.x;
    int lane = tid & 63, wv = tid >> 6;
    int col = lane & 15, quad = lane >> 4;
    int g = (img < NQ) ? 0 : 1 + (img - NQ) / SHOT;
    if constexpr (!BNIN) {
        const unsigned short* ib = (const unsigned short*)inv + (size_t)img * P * 64;
        for (int u = tid; u < SPAN * 8; u += 256) {
            int pix = u >> 3, part = u & 7;
            int p = p0 - S - 1 + pix;
            short8 v = {0, 0, 0, 0, 0, 0, 0, 0};
            if (p >= 0 && p < P) v = *(const short8*)(ib + (size_t)p * 64 + part * 8);
            *(short8*)(ls + pix * 72 + part * 8) = v;
        }
    } else {
        // fused BN+LReLU on fp32 input during staging (part = tid&7 is loop-invariant)
        const float* ib = (const float*)inv + (size_t)img * P * 64;
        int part = tid & 7;
        float ba[8], bb[8];
        #pragma unroll
        for (int j = 0; j < 8; ++j) {
            float2 ab = ((const float2*)msin)[g * 64 + part * 8 + j];
            ba[j] = ab.x;
            bb[j] = ab.y;
        }
        for (int u = tid; u < SPAN * 8; u += 256) {
            int pix = u >> 3;
            int p = p0 - S - 1 + pix;
            union { unsigned short us[8]; short8 s8; } o;
            #pragma unroll
            for (int j = 0; j < 8; ++j) o.us[j] = 0;
            if (p >= 0 && p < P) {
                const float* src = ib + (size_t)p * 64 + part * 8;
                float4 x0 = *(const float4*)src;
                float4 x1 = *(const float4*)(src + 4);
                float xs[8] = {x0.x, x0.y, x0.z, x0.w, x1.x, x1.y, x1.z, x1.w};
                #pragma unroll
                for (int j = 0; j < 8; ++j) {
                    float v = fmaf(xs[j], ba[j], bb[j]);
                    v = fmaxf(v, SLOPE * v);       // LeakyReLU
                    o.us[j] = bf16bits(v);
                }
            }
            *(short8*)(ls + pix * 72 + part * 8) = o.s8;
        }
    }
    __syncthreads();
    f32x4 acc[MT][4];
    #pragma unroll
    for (int mt = 0; mt < MT; ++mt)
        #pragma unroll
        for (int nt = 0; nt < 4; ++nt) acc[mt][nt] = (f32x4){0.f, 0.f, 0.f, 0.f};
    bool mok0[MT], mok2[MT];
    #pragma unroll
    for (int mt = 0; mt < MT; ++mt) {
        int xm = (p0 + wv * (MT * 16) + mt * 16 + col) % S;
        mok0[mt] = xm >= 1;
        mok2[mt] = xm <= S - 2;
    }
    const short8* wb = (const short8*)wpk;
    #pragma unroll
    for (int ky = 0; ky < 3; ++ky) {
        #pragma unroll
        for (int kx = 0; kx < 3; ++kx) {
            int t = ky * 3 + kx;
            int d = (ky - 1) * S + (kx - 1);
            #pragma unroll
            for (int half = 0; half < 2; ++half) {
                short8 b[4];
                #pragma unroll
                for (int nt = 0; nt < 4; ++nt)
                    b[nt] = wb[((t * 2 + half) * 4 + nt) * 64 + lane];
                #pragma unroll
                for (int mt = 0; mt < MT; ++mt) {
                    int idx = wv * (MT * 16) + mt * 16 + col + S + 1 + d;
                    short8 a = *(const short8*)(ls + idx * 72 + half * 32 + quad * 8);
                    bool ok = (kx == 0) ? mok0[mt] : (kx == 2) ? mok2[mt] : true;
                    if (!ok) a = (short8){0, 0, 0, 0, 0, 0, 0, 0};
                    #pragma unroll
                    for (int nt = 0; nt < 4; ++nt)
                        acc[mt][nt] = __builtin_amdgcn_mfma_f32_16x16x32_bf16(a, b[nt], acc[mt][nt], 0, 0, 0);
                }
            }
        }
    }
    float s[4] = {0.f, 0.f, 0.f, 0.f}, s2[4] = {0.f, 0.f, 0.f, 0.f};
    OT* ob = out + (size_t)img * P * 64;
    #pragma unroll
    for (int mt = 0; mt < MT; ++mt) {
        int tb = p0 + wv * (MT * 16) + mt * 16 + quad * 4;
        #pragma unroll
        for (int reg = 0; reg < 4; ++reg) {
            int pr = tb + reg;
            if (pr < P) {
                #pragma unroll
                for (int nt = 0; nt < 4; ++nt) {
                    float v = acc[mt][nt][reg];
                    stf(ob + (size_t)pr * 64 + nt * 16 + col, v);
                    s[nt] += v;
                    s2[nt] = fmaf(v, v, s2[nt]);
                }
            }
        }
    }
    #pragma unroll
    for (int d = 16; d < 64; d <<= 1)
        #pragma unroll
        for (int nt = 0; nt < 4; ++nt) {
            s[nt] += __shfl_xor(s[nt], d, 64);
            s2[nt] += __shfl_xor(s2[nt], d, 64);
        }
    if (quad == 0) {
        #pragma unroll
        for (int nt = 0; nt < 4; ++nt) {
            qs[wv][nt * 16 + col] = s[nt];
            qs2[wv][nt * 16 + col] = s2[nt];
        }
    }
    __syncthreads();
    if (wv == 0) {
        int rep = blockIdx.x & (NREP - 1);
        float ts = qs[0][lane] + qs[1][lane] + qs[2][lane] + qs[3][lane];
        float ts2 = qs2[0][lane] + qs2[1][lane] + qs2[2][lane] + qs2[3][lane];
        float* base = sums + ((size_t)(g * 64 + lane) * 2) * NREP + rep;
        atomicAdd(base, ts);
        atomicAdd(base + NREP, ts2);
    }
}

// fold (mean, invstd, gamma, beta) -> (a, b): y = x*a + b   (sums has NREP replicas)
__global__ void finalize_k(const float* __restrict__ sums, float* __restrict__ ms,
                           const float* __restrict__ gamma, const float* __restrict__ beta, int P)
{
    int i = blockIdx.x * blockDim.x + threadIdx.x;
    if (i >= 6 * 64) return;
    int g = i >> 6, c = i & 63;
    const float* ps = sums + (size_t)i * 2 * NREP;
    float s = 0.f, s2 = 0.f;
    #pragma unroll
    for (int r = 0; r < NREP; ++r) { s += ps[r]; s2 += ps[NREP + r]; }
    float cnt = (float)((g == 0 ? NQ : SHOT) * P);
    float mean = s / cnt;
    float var = s2 / cnt - mean * mean;
    float a = rsqrtf(var + EPSB) * gamma[c];
    ms[i * 2] = a;
    ms[i * 2 + 1] = fmaf(-mean, a, beta[c]);
}

// ---------------- BN + LeakyReLU + 2x2 maxpool -> bf16 ----------------
template <typename T>
__global__ __launch_bounds__(256) void bnpool_k(const T* __restrict__ x, const float* __restrict__ ms,
                                                __hip_bfloat16* __restrict__ out, int Win)
{
    int Wout = Win >> 1, Pout = Wout * Wout;
    size_t idx = (size_t)blockIdx.x * 256 + threadIdx.x;
    size_t total = (size_t)NIMG * Pout * 64;
    if (idx >= total) return;
    int c = (int)(idx & 63);
    size_t t = idx >> 6;
    int p = (int)(t % Pout);
    int img = (int)(t / Pout);
    int y = p / Wout, xo = p - y * Wout;
    int g = (img < NQ) ? 0 : 1 + (img - NQ) / SHOT;
    float a = ms[(g * 64 + c) * 2], bb = ms[(g * 64 + c) * 2 + 1];
    const T* base = x + (((size_t)img * Win + 2 * y) * Win + 2 * xo) * 64 + c;
    float mx = -3.4e38f;
    #pragma unroll
    for (int dy = 0; dy < 2; ++dy)
        #pragma unroll
        for (int dx = 0; dx < 2; ++dx) {
            float v = ldf(base + ((size_t)dy * Win + dx) * 64);
            v = fmaf(v, a, bb);
            v = v >= 0.f ? v : SLOPE * v;
            mx = fmaxf(mx, v);
        }
    out[idx] = __float2bfloat16(mx);
}

// ---------------- BN4 + LeakyReLU + per-pixel L2-normalize -> bf16 ----------------
__global__ __launch_bounds__(256) void bnnorm_k(const float* __restrict__ x, const float* __restrict__ ms,
                                                __hip_bfloat16* __restrict__ out)
{
    int lane = threadIdx.x & 63, wvr = threadIdx.x >> 6;
    int pix = blockIdx.x * 4 + wvr;        // one wave per pixel
    if (pix >= NIMG * P3) return;
    int img = pix / P3;
    int g = (img < NQ) ? 0 : 1 + (img - NQ) / SHOT;
    float v = fmaf(x[(size_t)pix * 64 + lane], ms[(g * 64 + lane) * 2], ms[(g * 64 + lane) * 2 + 1]);
    v = v >= 0.f ? v : SLOPE * v;
    float ss = v * v;
    #pragma unroll
    for (int d = 32; d > 0; d >>= 1) ss += __shfl_xor(ss, d, 64);
    out[(size_t)pix * 64 + lane] = __float2bfloat16(v * rsqrtf(ss));
}

// ---------------- similarity (R10 config): m-split blocks, partial top-3 + merge ----------
__device__ __forceinline__ void ins3(float v, float& t0, float& t1, float& t2)
{
    float n1 = __builtin_amdgcn_fmed3f(v, t0, t1);
    float n2 = __builtin_amdgcn_fmed3f(v, t1, t2);
    t0 = fmaxf(t0, v);
    t1 = n1;
    t2 = n2;
}

// grid: bq(32) x n(5) x qb(7) x mr(4) = 4480 blocks; block: 64q (wave=16q) x 576-row m-range
// Tail m-rows (m>=MM) are staged ZERO -> sim contribution 0, never in top-3 (sims in [-1,1]
// with abundant positives), so no bias path is needed.
// part layout: ((((bq*5+n)*7+qb)*4+mr)*64+ql)*3
__global__ __launch_bounds__(256) void sim_part_k(const __hip_bfloat16* __restrict__ fhat,
                                                  float* __restrict__ part)
{
    __shared__ __align__(16) unsigned short sl[64 * 72];   // 64 m-rows, 72-ushort stride
    int t = blockIdx.x;
    int mr = t & 3;
    int qb = (t >> 2) % 7;
    int n = (t / 28) % NCLS;
    int bq = t / (28 * NCLS);
    int tid = threadIdx.x, lane = tid & 63, wv = tid >> 6;
    int col = lane & 15, quad = lane >> 4;
    int q = qb * 64 + wv * 16 + col;
    int qc = q < P3 ? q : P3 - 1;
    const unsigned short* qp = (const unsigned short*)fhat + ((size_t)bq * P3 + qc) * 64;
    short8 a0 = *(const short8*)(qp + quad * 8);
    short8 a1 = *(const short8*)(qp + 32 + quad * 8);
    const unsigned short* sp = (const unsigned short*)fhat + (size_t)(NQ + n * SHOT) * P3 * 64;
    int m_lo = mr * MSPAN;
    int m_cnt = MM - m_lo; if (m_cnt > MSPAN) m_cnt = MSPAN;
    int nch = (m_cnt + 63) >> 6;
    float t0[4], t1[4], t2[4];
    #pragma unroll
    for (int r = 0; r < 4; ++r) { t0[r] = NEGINF; t1[r] = NEGINF; t2[r] = NEGINF; }
    int srow = tid >> 3, scc = (tid & 7) * 8;
    for (int c = 0; c < nch; ++c) {
        int m0 = m_lo + c * 64;
        __syncthreads();
        #pragma unroll
        for (int pass = 0; pass < 2; ++pass) {
            int row = srow + pass * 32;
            int m = m0 + row;
            short8 vv = {0, 0, 0, 0, 0, 0, 0, 0};
            if (m < MM) vv = *(const short8*)(sp + (size_t)m * 64 + scc);
            *(short8*)(sl + row * 72 + scc) = vv;
        }
        __syncthreads();
        const unsigned short* sr = sl + col * 72 + quad * 8;
        #pragma unroll
        for (int mt = 0; mt < 4; ++mt) {
            if (m0 + mt * 16 < MM) {            // wave-uniform: skip fully-fake tiles
                short8 b0 = *(const short8*)(sr);
                short8 b1 = *(const short8*)(sr + 32);
                f32x4 acc = {0.f, 0.f, 0.f, 0.f};
                acc = __builtin_amdgcn_mfma_f32_16x16x32_bf16(a0, b0, acc, 0, 0, 0);
                acc = __builtin_amdgcn_mfma_f32_16x16x32_bf16(a1, b1, acc, 0, 0, 0);
                #pragma unroll
                for (int r = 0; r < 4; ++r) ins3(acc[r], t0[r], t1[r], t2[r]);
            }
            sr += 16 * 72;
        }
    }
    // merge top-3 across the 16 col-lanes (m), same q per (quad, r)
    #pragma unroll
    for (int d = 1; d < 16; d <<= 1)
        #pragma unroll
        for (int r = 0; r < 4; ++r) {
            float u0 = __shfl_xor(t0[r], d, 64);
            float u1 = __shfl_xor(t1[r], d, 64);
            float u2 = __shfl_xor(t2[r], d, 64);
            ins3(u0, t0[r], t1[r], t2[r]);
            ins3(u1, t0[r], t1[r], t2[r]);
            ins3(u2, t0[r], t1[r], t2[r]);
        }
    if (col == 0) {
        #pragma unroll
        for (int r = 0; r < 4; ++r) {
            int ql = wv * 16 + quad * 4 + r;
            float* pp = part + ((((size_t)(bq * NCLS + n) * 7 + qb) * 4 + mr) * 64 + ql) * 3;
            pp[0] = t0[r];
            pp[1] = t1[r];
            pp[2] = t2[r];
        }
    }
}

// one block per (bq, n): merge 4 m-range partials per q, sum top-3, write out directly
__global__ __launch_bounds__(256) void sim_merge_k(const float* __restrict__ part,
                                                   float* __restrict__ out)
{
    __shared__ float red[4];
    int b = blockIdx.x;                    // bq*NCLS + n
    int tid = threadIdx.x, lane = tid & 63, wv = tid >> 6;
    float s = 0.f;
    for (int q = tid; q < P3; q += 256) {
        int qb = q >> 6, ql = q & 63;
        const float* pp = part + (((size_t)b * 7 + qb) * 4 * 64 + ql) * 3;
        float v0 = pp[0], v1 = pp[1], v2 = pp[2];
        #pragma unroll
        for (int mr = 1; mr < 4; ++mr) {
            const float* pm = pp + (size_t)mr * 192;
            ins3(pm[0], v0, v1, v2);
            ins3(pm[1], v0, v1, v2);
            ins3(pm[2], v0, v1, v2);
        }
        s += v0 + v1 + v2;
    }
    #pragma unroll
    for (int d = 32; d > 0; d >>= 1) s += __shfl_xor(s, d, 64);
    if (lane == 0) red[wv] = s;
    __syncthreads();
    if (tid == 0) out[b] = red[0] + red[1] + red[2] + red[3];
}

extern "C" void kernel_launch(void* const* d_in, const int* in_sizes, int n_in,
                              void* d_out, int out_size, void* d_ws, size_t ws_size,
                              hipStream_t stream)
{
    const float* input1 = (const float*)d_in[0];
    const float* input2 = (const float*)d_in[1];
    const float* w1 = (const float*)d_in[2];
    const float* g1 = (const float*)d_in[3];
    const float* b1 = (const float*)d_in[4];
    const float* w2 = (const float*)d_in[5];
    const float* g2 = (const float*)d_in[6];
    const float* b2 = (const float*)d_in[7];
    const float* w3 = (const float*)d_in[8];
    const float* g3 = (const float*)d_in[9];
    const float* b3 = (const float*)d_in[10];
    const float* w4 = (const float*)d_in[11];
    const float* g4 = (const float*)d_in[12];
    const float* b4 = (const float*)d_in[13];
    float* out = (float*)d_out;

    char* w8 = (char*)d_ws;
    const size_t oB = 51480576;
    const size_t oT = oB + 12870144;
    const size_t STG = 6 * 64 * 2 * NREP * sizeof(float);   // 98304 B per stage
    __hip_bfloat16* conv1raw = (__hip_bfloat16*)(w8 + 0);   // 51.5MB bf16
    __hip_bfloat16* conv2raw = (__hip_bfloat16*)(w8 + 0);   // reuse: 12.87MB bf16
    float* conv3raw = (float*)(w8 + 0);                     // reuse: 6.43MB fp32
    float* conv4raw = (float*)(w8 + 9652608);               // 6.43MB fp32
    __hip_bfloat16* fhat = (__hip_bfloat16*)(w8 + 16087680);
    __hip_bfloat16* pooled1 = (__hip_bfloat16*)(w8 + oB);   // 12.87MB
    __hip_bfloat16* pooled2 = (__hip_bfloat16*)(w8 + oB);   // reuse (3.2MB)
    float* sums = (float*)(w8 + oT);                        // 4 stages x 98304 B
    float* ms = (float*)(w8 + oT + 4 * STG);
    unsigned short* wpk2 = (unsigned short*)(w8 + oT + 4 * STG + 12288);
    unsigned short* wpk3 = (unsigned short*)(w8 + oT + 4 * STG + 12288 + 73728);
    unsigned short* wpk4 = (unsigned short*)(w8 + oT + 4 * STG + 12288 + 147456);
    unsigned short* wpk1 = (unsigned short*)(w8 + oT + 4 * STG + 12288 + 221184);
    const size_t oP = oT + 4 * STG + 12288 + 221184 + 8192;
    float* part = (float*)(w8 + oP);                        // 32*5*7*4*64*3 f32 = 3.44MB
    if (ws_size < oP + (size_t)NQ * NCLS * 7 * MRNG * 64 * 3 * sizeof(float)) return;
    float* sums1 = sums;
    float* sums2 = sums + 6 * 64 * 2 * NREP;
    float* sums3 = sums2 + 6 * 64 * 2 * NREP;
    float* sums4 = sums3 + 6 * 64 * 2 * NREP;

    // pack weights + zero stats (no memsets needed; sim_merge overwrites all of d_out)
    pack_all_k<<<448, 256, 0, stream>>>(w1, w2, w3, w4, wpk1, wpk2, wpk3, wpk4, sums);

    // stage 1: conv1 MFMA (+stats) -> finalize -> BN+LReLU+pool (84 -> 42)
    conv1m_k<<<NIMG * 28, 256, 0, stream>>>(input1, input2, wpk1, conv1raw, sums1);
    finalize_k<<<2, 256, 0, stream>>>(sums1, ms + 0, g1, b1, P1);
    bnpool_k<__hip_bfloat16><<<25137, 256, 0, stream>>>(conv1raw, ms + 0, pooled1, 84);
    // stage 2: conv2 MFMA (+stats, bf16 out) -> finalize -> BN+LReLU+pool (42 -> 21)
    conv64m_k<42, 256, false, __hip_bfloat16><<<NIMG * 7, 256, 0, stream>>>(
        pooled1, wpk2, conv2raw, sums2, nullptr);
    finalize_k<<<2, 256, 0, stream>>>(sums2, ms + 768, g2, b2, P2);
    bnpool_k<__hip_bfloat16><<<6285, 256, 0, stream>>>(conv2raw, ms + 768, pooled2, 42);
    // stage 3: conv3 MFMA (+stats) -> finalize   (no separate bnact: fused into conv4 staging)
    conv64m_k<21, 128, false, float><<<NIMG * 4, 256, 0, stream>>>(
        pooled2, wpk3, conv3raw, sums3, nullptr);
    finalize_k<<<2, 256, 0, stream>>>(sums3, ms + 1536, g3, b3, P3);
    // stage 4: conv4 MFMA with BN3+LReLU fused into staging (+stats) -> finalize -> normalize
    conv64m_k<21, 128, true, float><<<NIMG * 4, 256, 0, stream>>>(
        conv3raw, wpk4, conv4raw, sums4, ms + 1536);
    finalize_k<<<2, 256, 0, stream>>>(sums4, ms + 2304, g4, b4, P3);
    bnnorm_k<<<6285, 256, 0, stream>>>(conv4raw, ms + 2304, fhat);
    // similarity: partial top-3 over m-ranges, then merge (writes d_out directly)
    sim_part_k<<<NQ * NCLS * 7 * MRNG, 256, 0, stream>>>(fhat, part);
    sim_merge_k<<<NQ * NCLS, 256, 0, stream>>>(part, out);
}